// Round 7
// baseline (1093.985 us; speedup 1.0000x reference)
//
#include <hip/hip_runtime.h>
#include <hip/hip_bf16.h>

// Llama attention block: B=2, S=2048, H=4096, NH=32, NKV=8, HD=128, GQA 4:1.
// Pipeline (bf16 MFMA, fp32 accumulate):
//   1. convert hidden + Wq/Wk/Wv (concat) + Wo to bf16
//   2. QKV = X @ Wqkv^T   (M=4096,N=6144,K=4096)  256^2 8-phase GEMM (m201 port)
//   3. RoPE (Q,K) + scatter; fold 1/sqrt(128) into Q
//   4. V transpose: QKV -> Vtg [b][hkv][128 d][2048 s]
//   5. flash attention (causal): QBLK=128, KV tile 64, dbuf LDS, paired blocks,
//      counted-vmcnt raw barriers (T3/T4), defer-max (T13), setprio (T5)
//   6. out = AttnOut @ Wo^T  (fp32 out), same 8-phase GEMM

typedef __bf16 bf16;
typedef __bf16 bf16x8 __attribute__((ext_vector_type(8)));
typedef float f32x4 __attribute__((ext_vector_type(4)));

#define UNROLL _Pragma("unroll")

__device__ __forceinline__ void async16(const bf16* g, bf16* l) {
  __builtin_amdgcn_global_load_lds(
      (const __attribute__((address_space(1))) void*)g,
      (__attribute__((address_space(3))) void*)l,
      16, 0, 0);
}

#define BARR { __builtin_amdgcn_s_barrier(); __builtin_amdgcn_sched_barrier(0); }
#define VMCNT(n) { asm volatile("s_waitcnt vmcnt(" #n ")" ::: "memory"); __builtin_amdgcn_sched_barrier(0); }

// ---------------- fp32 -> bf16 convert (8 elem/thread) ----------------
__global__ void k_cvt(const float* __restrict__ s, bf16* __restrict__ d, int n8) {
  int i = blockIdx.x * 256 + threadIdx.x;
  if (i >= n8) return;
  const float4* sp = (const float4*)s + (size_t)i * 2;
  float4 a = sp[0], b = sp[1];
  bf16x8 o = { (bf16)a.x, (bf16)a.y, (bf16)a.z, (bf16)a.w,
               (bf16)b.x, (bf16)b.y, (bf16)b.z, (bf16)b.w };
  *(bf16x8*)(d + (size_t)i * 8) = o;
}

// ---------------- 256^2 8-phase GEMM (m201 port): C = A * Bw^T -----------
template <typename OutT>
__global__ __launch_bounds__(512, 2) void k_gemm8p(
    const bf16* __restrict__ A, const bf16* __restrict__ Bw,
    OutT* __restrict__ C, int K, int N, int nbx) {
  __shared__ __align__(16) bf16 lds[2][4][8192];  // 128 KiB
  const int tid = threadIdx.x;
  const int lane = tid & 63;
  const int w = tid >> 6;
  const int wm = w >> 2, wn = w & 3;  // 2M x 4N, wave out 128x64
  const int l16 = lane & 15, lh = lane >> 4;

  const int cpx = gridDim.x >> 3;
  const int swz = (blockIdx.x & 7) * cpx + (blockIdx.x >> 3);
  const int by = swz / nbx, bx = swz % nbx;
  const size_t m0 = (size_t)by * 256, n0 = (size_t)bx * 256;

  const int row0 = tid >> 2;
  const int cOff = ((tid & 3) ^ ((row0 >> 1) & 3)) * 8;
  const bf16* pA0 = A + (m0 + row0) * K + cOff;
  const bf16* pA1 = pA0 + (size_t)128 * K;
  const bf16* pB0 = Bw + (n0 + row0) * K + cOff;
  const bf16* pB1 = pB0 + (size_t)128 * K;

#define SA(s, h, t)                                        \
  { const int kk = (t) * 64 + (h) * 32;                    \
    async16(pA0 + kk, &lds[s][h][0] + tid * 8);            \
    async16(pA1 + kk, &lds[s][h][0] + 4096 + tid * 8); }
#define SB(s, h, t)                                        \
  { const int kk = (t) * 64 + (h) * 32;                    \
    async16(pB0 + kk, &lds[s][2 + (h)][0] + tid * 8);      \
    async16(pB1 + kk, &lds[s][2 + (h)][0] + 4096 + tid * 8); }

#define RDA(s, u, mh)                                                 \
  UNROLL for (int x = 0; x < 4; ++x) {                                \
    int p = (wm * 128 + (mh) * 64 + x * 16 + l16) * 64 + lh * 16;     \
    p ^= ((p >> 7) & 3) << 4;                                         \
    Ar[x] = *(const bf16x8*)((const char*)&lds[s][u][0] + p);         \
  }
#define RDB(s, u)                                                     \
  UNROLL for (int y = 0; y < 4; ++y) {                                \
    int p = (wn * 64 + y * 16 + l16) * 64 + lh * 16;                  \
    p ^= ((p >> 7) & 3) << 4;                                         \
    Br[y] = *(const bf16x8*)((const char*)&lds[s][u][0] + p);         \
  }
#define MF(mh)                                                        \
  { asm volatile("s_waitcnt lgkmcnt(0)" ::: "memory");                \
    __builtin_amdgcn_sched_barrier(0);                                \
    __builtin_amdgcn_s_setprio(1);                                    \
    UNROLL for (int x = 0; x < 4; ++x)                                \
      UNROLL for (int y = 0; y < 4; ++y)                              \
        acc[(mh) * 4 + x][y] = __builtin_amdgcn_mfma_f32_16x16x32_bf16( \
            Ar[x], Br[y], acc[(mh) * 4 + x][y], 0, 0, 0);             \
    __builtin_amdgcn_s_setprio(0); }

  f32x4 acc[8][4] = {};
  const int NITER = K >> 7;

  SA(0, 0, 0); SB(0, 0, 0); SA(0, 1, 0); SB(0, 1, 0); SA(1, 0, 1); SB(1, 0, 1);
  VMCNT(4);
  BARR;

#define ITER_BODY(i, LAST)                                                  \
  { const int t0 = 2 * (i), t1 = t0 + 1;                                    \
    bf16x8 Ar[4], Br[4];                                                    \
    RDA(0, 0, 0); RDB(0, 2); SA(1, 1, t1); BARR; MF(0); BARR;               \
    RDA(0, 0, 1); SB(1, 1, t1); BARR; MF(1); BARR;                          \
    RDA(0, 1, 0); RDB(0, 3); if (!(LAST)) SA(0, 0, t0 + 2);                 \
    BARR; MF(0); BARR;                                                      \
    RDA(0, 1, 1); if (!(LAST)) SB(0, 0, t0 + 2);                            \
    if (LAST) { VMCNT(0); } else { VMCNT(4); }                              \
    BARR; MF(1); BARR;                                                      \
    RDA(1, 0, 0); RDB(1, 2); if (!(LAST)) SA(0, 1, t0 + 2);                 \
    BARR; MF(0); BARR;                                                      \
    RDA(1, 0, 1); if (!(LAST)) SB(0, 1, t0 + 2); BARR; MF(1); BARR;         \
    RDA(1, 1, 0); RDB(1, 3); if (!(LAST)) SA(1, 0, t1 + 2);                 \
    BARR; MF(0); BARR;                                                      \
    RDA(1, 1, 1); if (!(LAST)) SB(1, 0, t1 + 2);                            \
    VMCNT(4); BARR; MF(1); BARR; }

  for (int i = 0; i < NITER - 1; ++i) ITER_BODY(i, 0);
  ITER_BODY(NITER - 1, 1);

  UNROLL for (int mi = 0; mi < 8; ++mi) {
    size_t row = m0 + wm * 128 + mi * 16 + lh * 4;
    UNROLL for (int ni = 0; ni < 4; ++ni) {
      size_t col = n0 + wn * 64 + ni * 16 + l16;
      UNROLL for (int j = 0; j < 4; ++j)
        C[(row + j) * N + col] = (OutT)acc[mi][ni][j];
    }
  }
#undef SA
#undef SB
#undef RDA
#undef RDB
#undef MF
#undef ITER_BODY
}

// ---------------- RoPE + scatter (Q,K only; V handled by k_vtrans) -------
__global__ void k_rope(const bf16* __restrict__ QKV, bf16* __restrict__ Qr,
                       bf16* __restrict__ Kr) {
  int gid = blockIdx.x * 256 + threadIdx.x;
  int p = gid & 63;
  int rest = gid >> 6;
  int slot = rest % 40;
  int tok = rest / 40;
  int s = tok & 2047;
  int b = tok >> 11;
  const bf16* src = QKV + (size_t)tok * 6144 + slot * 128;
  float x1 = (float)src[p], x2 = (float)src[p + 64];
  float f = exp2f((float)p * (-13.287712379549449f / 64.0f));
  float ang = (float)s * f;
  float sn, cn;
  sincosf(ang, &sn, &cn);
  float o1 = x1 * cn - x2 * sn;
  float o2 = x2 * cn + x1 * sn;
  bf16* dst;
  if (slot < 32) {
    o1 *= 0.08838834764831845f;
    o2 *= 0.08838834764831845f;
    dst = Qr + (((size_t)b * 32 + slot) * 2048 + s) * 128;
  } else {
    dst = Kr + (((size_t)b * 8 + (slot - 32)) * 2048 + s) * 128;
  }
  dst[p] = (bf16)o1;
  dst[p + 64] = (bf16)o2;
}

// ---------------- V transpose: QKV[tok][5120+hkv*128+d] -> Vtg[b][hkv][d][s]
__global__ void k_vtrans(const bf16* __restrict__ QKV, bf16* __restrict__ Vtg) {
  __shared__ __align__(16) bf16 T[64 * 64];
  const int tid = threadIdx.x;
  const int dt = blockIdx.x & 1;
  const int st = (blockIdx.x >> 1) & 31;
  const int hh = blockIdx.x >> 6;
  const int hkv = hh & 7, b = hh >> 3;
  const int s0 = st * 64, d0 = dt * 64;
  const bf16* src = QKV + (size_t)(b * 2048 + s0) * 6144 + 5120 + hkv * 128 + d0;
  UNROLL for (int k = 0; k < 2; ++k) {
    int cc = tid * 2 + k;
    int r = cc >> 3, c8 = cc & 7;
    bf16x8 v = *(const bf16x8*)(src + (size_t)r * 6144 + c8 * 8);
    int byte = (r * 128 + c8 * 16) ^ ((r & 7) << 4);
    *(bf16x8*)((char*)T + byte) = v;
  }
  __syncthreads();
  bf16* dst = Vtg + ((size_t)(b * 8 + hkv) * 128 + d0) * 2048 + s0;
  UNROLL for (int k = 0; k < 2; ++k) {
    int cc = tid * 2 + k;
    int d = cc >> 3, s8 = cc & 7;
    bf16x8 v;
    UNROLL for (int j = 0; j < 8; ++j) {
      int s = s8 * 8 + j;
      int byte = (s * 128 + d * 2) ^ ((s & 7) << 4);
      v[j] = *(const bf16*)((const char*)T + byte);
    }
    *(bf16x8*)(dst + (size_t)d * 2048 + s8 * 8) = v;
  }
}

// ---------------- flash attention (causal, GQA 4:1) ----------------
// grid 512: block = (b, h, pair {pid, 15-pid}), 128 q-rows per q-block.
// 4 waves x 32 rows. KV tile 64, double-buffered LDS.
// T3/T4: raw s_barrier + vmcnt(8) (next tile's 8 loads stay in flight
// across barriers; only the last tile drains to 0).
// T13: defer-max THR=8 (skip rescale when wave-uniform max growth <= 8).
// T5: setprio(1) around QK and PV MFMA clusters.
__global__ __launch_bounds__(256, 2) void k_flash(
    const bf16* __restrict__ Qr, const bf16* __restrict__ Kr,
    const bf16* __restrict__ Vtg, bf16* __restrict__ Out) {
  __shared__ __align__(16) bf16 Kl[2][64 * 128];
  __shared__ __align__(16) bf16 Vl[2][128 * 64];
  __shared__ __align__(16) bf16 Pl[4][32 * 64];
  const int tid = threadIdx.x;
  const int lane = tid & 63;
  const int w = tid >> 6;
  const int l16 = lane & 15, lh = lane >> 4;
  const int pid = blockIdx.x & 7;
  const int hl = blockIdx.x >> 3;
  const int h = hl & 31, b = hl >> 5;
  const int hkv = h >> 2;
  const bf16* Kbase = Kr + ((size_t)(b * 8 + hkv)) * 2048 * 128;
  const bf16* Vbase = Vtg + ((size_t)(b * 8 + hkv)) * 128 * 2048;
  bf16* P = &Pl[w][0];

  int kOff[4], vOff[4], ldsOff[4];
  UNROLL for (int i = 0; i < 4; ++i) {
    int c = (w * 4 + i) * 64 + lane;
    ldsOff[i] = c * 8;
    int r = c >> 4, p = c & 15;
    kOff[i] = r * 128 + (p ^ (r & 7)) * 8;
    int r2 = c >> 3, p2 = c & 7;
    vOff[i] = r2 * 2048 + (p2 ^ (r2 & 7)) * 8;
  }

#define STAGE(buf, nb)                                                    \
  UNROLL for (int i = 0; i < 4; ++i) {                                    \
    async16(Kbase + (size_t)(nb) * 8192 + kOff[i], &Kl[buf][0] + ldsOff[i]); \
    async16(Vbase + (size_t)(nb) * 64 + vOff[i], &Vl[buf][0] + ldsOff[i]);   \
  }

  for (int qi = 0; qi < 2; ++qi) {
    const int q = qi ? (15 - pid) : pid;
    const int q0 = q * 128;
    const int nt = 2 * q + 2;

    bf16x8 qf[2][4];
    UNROLL for (int m = 0; m < 2; ++m) {
      const bf16* qb = Qr + (((size_t)(b * 32 + h)) * 2048 + q0 + w * 32 + m * 16 + l16) * 128 + lh * 8;
      UNROLL for (int kc = 0; kc < 4; ++kc) qf[m][kc] = *(const bf16x8*)(qb + kc * 32);
    }
    f32x4 acc[2][8] = {};
    float mrow[2][4] = {{-1e30f, -1e30f, -1e30f, -1e30f}, {-1e30f, -1e30f, -1e30f, -1e30f}};
    float lrow[2][4] = {};

    // prologue: tile 0 into buf 0, full drain once
    STAGE(0, 0);
    VMCNT(0);
    BARR;

    for (int t = 0; t < nt; ++t) {
      const int cur = t & 1;
      if (t + 1 < nt) {
        STAGE(cur ^ 1, t + 1);
        VMCNT(8);   // drain tile t's 8 loads; keep t+1's 8 in flight
      } else {
        VMCNT(0);
      }
      BARR;  // all waves' tile-t data now visible

      // S = Q K^T
      f32x4 sf[2][4] = {};
      __builtin_amdgcn_s_setprio(1);
      UNROLL for (int ni = 0; ni < 4; ++ni) {
        int row = ni * 16 + l16;
        bf16x8 kf[4];
        UNROLL for (int kc = 0; kc < 4; ++kc) {
          int byte = (row * 256 + kc * 64 + lh * 16) ^ ((row & 7) << 4);
          kf[kc] = *(const bf16x8*)((const char*)&Kl[cur][0] + byte);
        }
        UNROLL for (int m = 0; m < 2; ++m)
          UNROLL for (int kc = 0; kc < 4; ++kc)
            sf[m][ni] = __builtin_amdgcn_mfma_f32_16x16x32_bf16(qf[m][kc], kf[kc], sf[m][ni], 0, 0, 0);
      }
      __builtin_amdgcn_s_setprio(0);

      // causal mask on diagonal tiles
      if (t >= 2 * q) {
        UNROLL for (int m = 0; m < 2; ++m)
          UNROLL for (int ni = 0; ni < 4; ++ni) {
            int key = t * 64 + ni * 16 + l16;
            UNROLL for (int j = 0; j < 4; ++j) {
              int rowg = q0 + w * 32 + m * 16 + lh * 4 + j;
              if (key > rowg) sf[m][ni][j] = -1e30f;
            }
          }
      }

      // tile row-max (per 16-lane group)
      float mx[2][4];
      UNROLL for (int m = 0; m < 2; ++m)
        UNROLL for (int j = 0; j < 4; ++j) {
          float v = fmaxf(fmaxf(sf[m][0][j], sf[m][1][j]), fmaxf(sf[m][2][j], sf[m][3][j]));
          v = fmaxf(v, __shfl_xor(v, 1));
          v = fmaxf(v, __shfl_xor(v, 2));
          v = fmaxf(v, __shfl_xor(v, 4));
          v = fmaxf(v, __shfl_xor(v, 8));
          mx[m][j] = v;
        }
      bool d = true;
      UNROLL for (int m = 0; m < 2; ++m)
        UNROLL for (int j = 0; j < 4; ++j) d = d && (mx[m][j] <= mrow[m][j] + 8.0f);
      if (__all(d)) {
        // defer-max: keep old max, no rescale (P bounded by e^8)
        UNROLL for (int m = 0; m < 2; ++m)
          UNROLL for (int j = 0; j < 4; ++j) {
            float rs = 0.f;
            UNROLL for (int ni = 0; ni < 4; ++ni) {
              float pv = __expf(sf[m][ni][j] - mrow[m][j]);
              sf[m][ni][j] = pv;
              rs += pv;
            }
            rs += __shfl_xor(rs, 1);
            rs += __shfl_xor(rs, 2);
            rs += __shfl_xor(rs, 4);
            rs += __shfl_xor(rs, 8);
            lrow[m][j] += rs;
          }
      } else {
        float corr[2][4];
        UNROLL for (int m = 0; m < 2; ++m)
          UNROLL for (int j = 0; j < 4; ++j) {
            float mn = fmaxf(mrow[m][j], mx[m][j]);
            corr[m][j] = __expf(mrow[m][j] - mn);
            mrow[m][j] = mn;
            float rs = 0.f;
            UNROLL for (int ni = 0; ni < 4; ++ni) {
              float pv = __expf(sf[m][ni][j] - mn);
              sf[m][ni][j] = pv;
              rs += pv;
            }
            rs += __shfl_xor(rs, 1);
            rs += __shfl_xor(rs, 2);
            rs += __shfl_xor(rs, 4);
            rs += __shfl_xor(rs, 8);
            lrow[m][j] = lrow[m][j] * corr[m][j] + rs;
          }
        UNROLL for (int m = 0; m < 2; ++m)
          UNROLL for (int di = 0; di < 8; ++di)
            UNROLL for (int j = 0; j < 4; ++j) acc[m][di][j] *= corr[m][j];
      }

      // P -> per-wave LDS (swizzled)
      UNROLL for (int m = 0; m < 2; ++m)
        UNROLL for (int ni = 0; ni < 4; ++ni)
          UNROLL for (int j = 0; j < 4; ++j) {
            int row = m * 16 + lh * 4 + j;
            int byte = (row * 128 + ni * 32 + l16 * 2) ^ ((row & 7) << 4);
            *(bf16*)((char*)P + byte) = (bf16)sf[m][ni][j];
          }
      // O += P @ V
      UNROLL for (int kc = 0; kc < 2; ++kc) {
        bf16x8 pa[2];
        UNROLL for (int m = 0; m < 2; ++m) {
          int row = m * 16 + l16;
          int byte = (row * 128 + kc * 64 + lh * 16) ^ ((row & 7) << 4);
          pa[m] = *(const bf16x8*)((const char*)P + byte);
        }
        __builtin_amdgcn_s_setprio(1);
        UNROLL for (int di = 0; di < 8; ++di) {
          int dd = di * 16 + l16;
          int byte = (dd * 128 + kc * 64 + lh * 16) ^ ((dd & 7) << 4);
          bf16x8 vb = *(const bf16x8*)((const char*)&Vl[cur][0] + byte);
          UNROLL for (int m = 0; m < 2; ++m)
            acc[m][di] = __builtin_amdgcn_mfma_f32_16x16x32_bf16(pa[m], vb, acc[m][di], 0, 0, 0);
        }
        __builtin_amdgcn_s_setprio(0);
      }
      BARR;  // all reads of buf[cur] done before next iter overwrites it
    }

    UNROLL for (int m = 0; m < 2; ++m)
      UNROLL for (int j = 0; j < 4; ++j) {
        float inv = 1.0f / lrow[m][j];
        int rowg = q0 + w * 32 + m * 16 + lh * 4 + j;
        bf16* ob = Out + ((size_t)(b * 2048) + rowg) * 4096 + h * 128 + l16;
        UNROLL for (int di = 0; di < 8; ++di)
          ob[di * 16] = (bf16)(acc[m][di][j] * inv);
      }
  }
#undef STAGE
}

// ---------------- launch ----------------
extern "C" void kernel_launch(void* const* d_in, const int* in_sizes, int n_in,
                              void* d_out, int out_size, void* d_ws, size_t ws_size,
                              hipStream_t stream) {
  const float* hidden = (const float*)d_in[0];
  const float* Wq = (const float*)d_in[3];
  const float* Wk = (const float*)d_in[4];
  const float* Wv = (const float*)d_in[5];
  const float* Wo = (const float*)d_in[6];
  float* out = (float*)d_out;

  char* ws = (char*)d_ws;
  if (ws_size < 184549376u) return;
  bf16* Xb = (bf16*)(ws);
  bf16* Wqkv = (bf16*)(ws + 33554432u);
  bf16* QKV = (bf16*)(ws + 83886080u);
  bf16* Qr = (bf16*)(ws + 134217728u);
  bf16* Kr = (bf16*)(ws + 167772160u);
  bf16* Vtg = (bf16*)(ws + 176160768u);
  bf16* AttnO = Xb;
  bf16* Wob = Wqkv;

  k_cvt<<<8192, 256, 0, stream>>>(hidden, Xb, 2097152);
  k_cvt<<<8192, 256, 0, stream>>>(Wq, Wqkv, 2097152);
  k_cvt<<<2048, 256, 0, stream>>>(Wk, Wqkv + 16777216u, 524288);
  k_cvt<<<2048, 256, 0, stream>>>(Wv, Wqkv + 20971520u, 524288);
  // QKV GEMM: 16 x 24 = 384 blocks (256^2 tiles) — round-5 best config
  k_gemm8p<bf16><<<384, 512, 0, stream>>>(Xb, Wqkv, QKV, 4096, 6144, 24);
  k_rope<<<40960, 256, 0, stream>>>(QKV, Qr, Kr);
  k_vtrans<<<1024, 256, 0, stream>>>(QKV, Vtg);
  k_cvt<<<8192, 256, 0, stream>>>(Wo, Wob, 2097152);
  k_flash<<<512, 256, 0, stream>>>(Qr, Kr, Vtg, AttnO);
  // O-proj: 16 x 16 = 256 blocks (exactly one dispatch wave)
  k_gemm8p<float><<<256, 512, 0, stream>>>(AttnO, Wob, out, 4096, 4096, 16);
}

// Round 8
// 602.019 us; speedup vs baseline: 1.8172x; 1.8172x over previous
//
#include <hip/hip_runtime.h>
#include <hip/hip_bf16.h>

// Llama attention block: B=2, S=2048, H=4096, NH=32, NKV=8, HD=128, GQA 4:1.
// Pipeline (bf16 MFMA, fp32 accumulate):
//   1. convert hidden + Wq/Wk/Wv (concat) + Wo to bf16
//   2. QKV = X @ Wqkv^T  (M=4096,N=6144,K=4096): 256^2 tile, BK=32,
//      4-deep LDS rotation (stage t+3 while computing t), counted vmcnt(8)
//   3. RoPE (Q,K) + scatter; fold 1/sqrt(128) into Q
//   4. V transpose: QKV -> Vtg [b][hkv][128 d][2048 s]
//   5. flash attention (causal), QBLK=128, KV tile 64, dbuf LDS, paired blocks
//      (round-5 version verbatim; round-7 variant spilled to scratch)
//   6. out = AttnOut @ Wo^T (fp32), same 4-deep GEMM

typedef __bf16 bf16;
typedef __bf16 bf16x8 __attribute__((ext_vector_type(8)));
typedef float f32x4 __attribute__((ext_vector_type(4)));

#define UNROLL _Pragma("unroll")

__device__ __forceinline__ void async16(const bf16* g, bf16* l) {
  __builtin_amdgcn_global_load_lds(
      (const __attribute__((address_space(1))) void*)g,
      (__attribute__((address_space(3))) void*)l,
      16, 0, 0);
}

#define BARR { __builtin_amdgcn_s_barrier(); __builtin_amdgcn_sched_barrier(0); }
#define VMCNT(n) { asm volatile("s_waitcnt vmcnt(" #n ")" ::: "memory"); __builtin_amdgcn_sched_barrier(0); }

// ---------------- fp32 -> bf16 convert (8 elem/thread) ----------------
__global__ void k_cvt(const float* __restrict__ s, bf16* __restrict__ d, int n8) {
  int i = blockIdx.x * 256 + threadIdx.x;
  if (i >= n8) return;
  const float4* sp = (const float4*)s + (size_t)i * 2;
  float4 a = sp[0], b = sp[1];
  bf16x8 o = { (bf16)a.x, (bf16)a.y, (bf16)a.z, (bf16)a.w,
               (bf16)b.x, (bf16)b.y, (bf16)b.z, (bf16)b.w };
  *(bf16x8*)(d + (size_t)i * 8) = o;
}

// ---------------- 256^2 4-deep GEMM: C[M,N] = A[M,K] * Bw[N,K]^T ---------
// 8 waves (2M x 4N), wave out 128x64. BK=32, 4 LDS sides rotate:
// side s = t&3 holds K-tile t's {A [256][32], B [256][32]} (32 KiB/side,
// 128 KiB total). While computing tile t, stage tile t+3 -> stage-to-read
// distance 6 phases; vmcnt(8) at phB demands only loads >=4 phases old.
// Swizzle within unit: byte p ^= ((p>>7)&3)<<4 (involution; inverse applied
// on global_load_lds source, forward on ds_read). Ledger:
//   phA: read A(mh0)+B of side s; stage A(t+3); barrier; 16 MFMA; barrier
//   phB: read A(mh1) (B reused in regs); stage B(t+3); vmcnt(8); barrier;
//        16 MFMA; barrier
// vmcnt(8) at t.phB = keep {A,B}(t+2),(t+3) (8 loads), force (t+1) landed.
// Tail: t=NT-3 vmcnt(4), t=NT-2 vmcnt(0), t=NT-1 none.
template <typename OutT>
__global__ __launch_bounds__(512, 2) void k_gemm4d(
    const bf16* __restrict__ A, const bf16* __restrict__ Bw,
    OutT* __restrict__ C, int K, int N, int nbx) {
  __shared__ __align__(16) bf16 lds[4][2][8192];  // 128 KiB
  const int tid = threadIdx.x;
  const int lane = tid & 63;
  const int w = tid >> 6;             // 0..7
  const int wm = w >> 2, wn = w & 3;  // 2M x 4N, wave out 128x64
  const int l16 = lane & 15, lh = lane >> 4;

  // XCD bijective swizzle (grid % 8 == 0)
  const int cpx = gridDim.x >> 3;
  const int swz = (blockIdx.x & 7) * cpx + (blockIdx.x >> 3);
  const int by = swz / nbx, bx = swz % nbx;
  const size_t m0 = (size_t)by * 256, n0 = (size_t)bx * 256;

  // staging constants: thread -> (row, inverse-swizzled k-slot)
  const int row0 = tid >> 2;
  const int cOff = ((tid & 3) ^ ((row0 >> 1) & 3)) * 8;
  const bf16* pA0 = A + (m0 + row0) * K + cOff;
  const bf16* pA1 = pA0 + (size_t)128 * K;
  const bf16* pB0 = Bw + (n0 + row0) * K + cOff;
  const bf16* pB1 = pB0 + (size_t)128 * K;

#define SA4(s, t)                                          \
  { const int kk = (t) * 32;                               \
    async16(pA0 + kk, &lds[s][0][0] + tid * 8);            \
    async16(pA1 + kk, &lds[s][0][0] + 4096 + tid * 8); }
#define SB4(s, t)                                          \
  { const int kk = (t) * 32;                               \
    async16(pB0 + kk, &lds[s][1][0] + tid * 8);            \
    async16(pB1 + kk, &lds[s][1][0] + 4096 + tid * 8); }

#define RDA4(s, mh)                                                   \
  UNROLL for (int x = 0; x < 4; ++x) {                                \
    int p = (wm * 128 + (mh) * 64 + x * 16 + l16) * 64 + lh * 16;     \
    p ^= ((p >> 7) & 3) << 4;                                         \
    Ar[x] = *(const bf16x8*)((const char*)&lds[s][0][0] + p);         \
  }
#define RDB4(s)                                                       \
  UNROLL for (int y = 0; y < 4; ++y) {                                \
    int p = (wn * 64 + y * 16 + l16) * 64 + lh * 16;                  \
    p ^= ((p >> 7) & 3) << 4;                                         \
    Br[y] = *(const bf16x8*)((const char*)&lds[s][1][0] + p);         \
  }
#define MF(mh)                                                        \
  { asm volatile("s_waitcnt lgkmcnt(0)" ::: "memory");                \
    __builtin_amdgcn_sched_barrier(0);                                \
    __builtin_amdgcn_s_setprio(1);                                    \
    UNROLL for (int x = 0; x < 4; ++x)                                \
      UNROLL for (int y = 0; y < 4; ++y)                              \
        acc[(mh) * 4 + x][y] = __builtin_amdgcn_mfma_f32_16x16x32_bf16( \
            Ar[x], Br[y], acc[(mh) * 4 + x][y], 0, 0, 0);             \
    __builtin_amdgcn_s_setprio(0); }

  f32x4 acc[8][4] = {};
  const int NT = K >> 5;  // K-tiles of 32

  // prologue: stage tiles 0,1,2 (12 loads); require tile 0 landed
  SA4(0, 0); SB4(0, 0); SA4(1, 1); SB4(1, 1); SA4(2, 2); SB4(2, 2);
  VMCNT(8); BARR;

  for (int t = 0; t < NT - 3; ++t) {
    const int s = t & 3, sp = (t + 3) & 3;
    bf16x8 Ar[4], Br[4];
    RDA4(s, 0); RDB4(s);
    SA4(sp, t + 3);
    BARR; MF(0); BARR;
    RDA4(s, 1);
    SB4(sp, t + 3);
    VMCNT(8);
    BARR; MF(1); BARR;
  }
  // tail: NT-3 (vmcnt 4), NT-2 (vmcnt 0), NT-1 (none)
  {
    const int s = (NT - 3) & 3;
    bf16x8 Ar[4], Br[4];
    RDA4(s, 0); RDB4(s); BARR; MF(0); BARR;
    RDA4(s, 1); VMCNT(4); BARR; MF(1); BARR;
  }
  {
    const int s = (NT - 2) & 3;
    bf16x8 Ar[4], Br[4];
    RDA4(s, 0); RDB4(s); BARR; MF(0); BARR;
    RDA4(s, 1); VMCNT(0); BARR; MF(1); BARR;
  }
  {
    const int s = (NT - 1) & 3;
    bf16x8 Ar[4], Br[4];
    RDA4(s, 0); RDB4(s); BARR; MF(0); BARR;
    RDA4(s, 1); BARR; MF(1);
  }

  // C write: row = m0 + wm*128 + mi*16 + lh*4 + j ; col = n0 + wn*64 + ni*16 + l16
  UNROLL for (int mi = 0; mi < 8; ++mi) {
    size_t row = m0 + wm * 128 + mi * 16 + lh * 4;
    UNROLL for (int ni = 0; ni < 4; ++ni) {
      size_t col = n0 + wn * 64 + ni * 16 + l16;
      UNROLL for (int j = 0; j < 4; ++j)
        C[(row + j) * N + col] = (OutT)acc[mi][ni][j];
    }
  }
#undef SA4
#undef SB4
#undef RDA4
#undef RDB4
#undef MF
}

// ---------------- RoPE + scatter (Q,K only; V handled by k_vtrans) -------
__global__ void k_rope(const bf16* __restrict__ QKV, bf16* __restrict__ Qr,
                       bf16* __restrict__ Kr) {
  int gid = blockIdx.x * 256 + threadIdx.x;
  int p = gid & 63;
  int rest = gid >> 6;
  int slot = rest % 40;
  int tok = rest / 40;
  int s = tok & 2047;
  int b = tok >> 11;
  const bf16* src = QKV + (size_t)tok * 6144 + slot * 128;
  float x1 = (float)src[p], x2 = (float)src[p + 64];
  float f = exp2f((float)p * (-13.287712379549449f / 64.0f));
  float ang = (float)s * f;
  float sn, cn;
  sincosf(ang, &sn, &cn);
  float o1 = x1 * cn - x2 * sn;
  float o2 = x2 * cn + x1 * sn;
  bf16* dst;
  if (slot < 32) {
    o1 *= 0.08838834764831845f;
    o2 *= 0.08838834764831845f;
    dst = Qr + (((size_t)b * 32 + slot) * 2048 + s) * 128;
  } else {
    dst = Kr + (((size_t)b * 8 + (slot - 32)) * 2048 + s) * 128;
  }
  dst[p] = (bf16)o1;
  dst[p + 64] = (bf16)o2;
}

// ---------------- V transpose: QKV[tok][5120+hkv*128+d] -> Vtg[b][hkv][d][s]
__global__ void k_vtrans(const bf16* __restrict__ QKV, bf16* __restrict__ Vtg) {
  __shared__ __align__(16) bf16 T[64 * 64];
  const int tid = threadIdx.x;
  const int dt = blockIdx.x & 1;
  const int st = (blockIdx.x >> 1) & 31;
  const int hh = blockIdx.x >> 6;
  const int hkv = hh & 7, b = hh >> 3;
  const int s0 = st * 64, d0 = dt * 64;
  const bf16* src = QKV + (size_t)(b * 2048 + s0) * 6144 + 5120 + hkv * 128 + d0;
  UNROLL for (int k = 0; k < 2; ++k) {
    int cc = tid * 2 + k;
    int r = cc >> 3, c8 = cc & 7;
    bf16x8 v = *(const bf16x8*)(src + (size_t)r * 6144 + c8 * 8);
    int byte = (r * 128 + c8 * 16) ^ ((r & 7) << 4);
    *(bf16x8*)((char*)T + byte) = v;
  }
  __syncthreads();
  bf16* dst = Vtg + ((size_t)(b * 8 + hkv) * 128 + d0) * 2048 + s0;
  UNROLL for (int k = 0; k < 2; ++k) {
    int cc = tid * 2 + k;
    int d = cc >> 3, s8 = cc & 7;
    bf16x8 v;
    UNROLL for (int j = 0; j < 8; ++j) {
      int s = s8 * 8 + j;
      int byte = (s * 128 + d * 2) ^ ((s & 7) << 4);
      v[j] = *(const bf16*)((const char*)T + byte);
    }
    *(bf16x8*)(dst + (size_t)d * 2048 + s8 * 8) = v;
  }
}

// ---------------- flash attention (causal, GQA 4:1) — round-5 version ----
__global__ __launch_bounds__(256, 2) void k_flash(
    const bf16* __restrict__ Qr, const bf16* __restrict__ Kr,
    const bf16* __restrict__ Vtg, bf16* __restrict__ Out) {
  __shared__ __align__(16) bf16 Kl[2][64 * 128];
  __shared__ __align__(16) bf16 Vl[2][128 * 64];
  __shared__ __align__(16) bf16 Pl[4][32 * 64];
  const int tid = threadIdx.x;
  const int lane = tid & 63;
  const int w = tid >> 6;
  const int l16 = lane & 15, lh = lane >> 4;
  const int pid = blockIdx.x & 7;
  const int hl = blockIdx.x >> 3;
  const int h = hl & 31, b = hl >> 5;
  const int hkv = h >> 2;
  const bf16* Kbase = Kr + ((size_t)(b * 8 + hkv)) * 2048 * 128;
  const bf16* Vbase = Vtg + ((size_t)(b * 8 + hkv)) * 128 * 2048;
  bf16* P = &Pl[w][0];

  int kOff[4], vOff[4], ldsOff[4];
  UNROLL for (int i = 0; i < 4; ++i) {
    int c = (w * 4 + i) * 64 + lane;
    ldsOff[i] = c * 8;
    int r = c >> 4, p = c & 15;
    kOff[i] = r * 128 + (p ^ (r & 7)) * 8;
    int r2 = c >> 3, p2 = c & 7;
    vOff[i] = r2 * 2048 + (p2 ^ (r2 & 7)) * 8;
  }

  for (int qi = 0; qi < 2; ++qi) {
    const int q = qi ? (15 - pid) : pid;
    const int q0 = q * 128;
    const int nt = 2 * q + 2;

    bf16x8 qf[2][4];
    UNROLL for (int m = 0; m < 2; ++m) {
      const bf16* qb = Qr + (((size_t)(b * 32 + h)) * 2048 + q0 + w * 32 + m * 16 + l16) * 128 + lh * 8;
      UNROLL for (int kc = 0; kc < 4; ++kc) qf[m][kc] = *(const bf16x8*)(qb + kc * 32);
    }
    f32x4 acc[2][8] = {};
    float mrow[2][4] = {{-1e30f, -1e30f, -1e30f, -1e30f}, {-1e30f, -1e30f, -1e30f, -1e30f}};
    float lrow[2][4] = {};

    UNROLL for (int i = 0; i < 4; ++i) {
      async16(Kbase + kOff[i], &Kl[0][0] + ldsOff[i]);
      async16(Vbase + vOff[i], &Vl[0][0] + ldsOff[i]);
    }
    __syncthreads();

    for (int t = 0; t < nt; ++t) {
      const int cur = t & 1;
      if (t + 1 < nt) {
        const int nb = t + 1;
        UNROLL for (int i = 0; i < 4; ++i) {
          async16(Kbase + (size_t)nb * 8192 + kOff[i], &Kl[cur ^ 1][0] + ldsOff[i]);
          async16(Vbase + (size_t)nb * 64 + vOff[i], &Vl[cur ^ 1][0] + ldsOff[i]);
        }
      }
      f32x4 sf[2][4] = {};
      UNROLL for (int ni = 0; ni < 4; ++ni) {
        int row = ni * 16 + l16;
        bf16x8 kf[4];
        UNROLL for (int kc = 0; kc < 4; ++kc) {
          int byte = (row * 256 + kc * 64 + lh * 16) ^ ((row & 7) << 4);
          kf[kc] = *(const bf16x8*)((const char*)&Kl[cur][0] + byte);
        }
        UNROLL for (int m = 0; m < 2; ++m)
          UNROLL for (int kc = 0; kc < 4; ++kc)
            sf[m][ni] = __builtin_amdgcn_mfma_f32_16x16x32_bf16(qf[m][kc], kf[kc], sf[m][ni], 0, 0, 0);
      }
      if (t >= 2 * q) {
        UNROLL for (int m = 0; m < 2; ++m)
          UNROLL for (int ni = 0; ni < 4; ++ni) {
            int key = t * 64 + ni * 16 + l16;
            UNROLL for (int j = 0; j < 4; ++j) {
              int rowg = q0 + w * 32 + m * 16 + lh * 4 + j;
              if (key > rowg) sf[m][ni][j] = -1e30f;
            }
          }
      }
      float corr[2][4];
      UNROLL for (int m = 0; m < 2; ++m)
        UNROLL for (int j = 0; j < 4; ++j) {
          float mx = fmaxf(fmaxf(sf[m][0][j], sf[m][1][j]), fmaxf(sf[m][2][j], sf[m][3][j]));
          mx = fmaxf(mx, __shfl_xor(mx, 1));
          mx = fmaxf(mx, __shfl_xor(mx, 2));
          mx = fmaxf(mx, __shfl_xor(mx, 4));
          mx = fmaxf(mx, __shfl_xor(mx, 8));
          float mn = fmaxf(mrow[m][j], mx);
          corr[m][j] = __expf(mrow[m][j] - mn);
          mrow[m][j] = mn;
          float rs = 0.f;
          UNROLL for (int ni = 0; ni < 4; ++ni) {
            float pv = __expf(sf[m][ni][j] - mn);
            sf[m][ni][j] = pv;
            rs += pv;
          }
          rs += __shfl_xor(rs, 1);
          rs += __shfl_xor(rs, 2);
          rs += __shfl_xor(rs, 4);
          rs += __shfl_xor(rs, 8);
          lrow[m][j] = lrow[m][j] * corr[m][j] + rs;
        }
      UNROLL for (int m = 0; m < 2; ++m)
        UNROLL for (int di = 0; di < 8; ++di)
          UNROLL for (int j = 0; j < 4; ++j) acc[m][di][j] *= corr[m][j];
      UNROLL for (int m = 0; m < 2; ++m)
        UNROLL for (int ni = 0; ni < 4; ++ni)
          UNROLL for (int j = 0; j < 4; ++j) {
            int row = m * 16 + lh * 4 + j;
            int byte = (row * 128 + ni * 32 + l16 * 2) ^ ((row & 7) << 4);
            *(bf16*)((char*)P + byte) = (bf16)sf[m][ni][j];
          }
      UNROLL for (int kc = 0; kc < 2; ++kc) {
        bf16x8 pa[2];
        UNROLL for (int m = 0; m < 2; ++m) {
          int row = m * 16 + l16;
          int byte = (row * 128 + kc * 64 + lh * 16) ^ ((row & 7) << 4);
          pa[m] = *(const bf16x8*)((const char*)P + byte);
        }
        UNROLL for (int di = 0; di < 8; ++di) {
          int d = di * 16 + l16;
          int byte = (d * 128 + kc * 64 + lh * 16) ^ ((d & 7) << 4);
          bf16x8 vb = *(const bf16x8*)((const char*)&Vl[cur][0] + byte);
          UNROLL for (int m = 0; m < 2; ++m)
            acc[m][di] = __builtin_amdgcn_mfma_f32_16x16x32_bf16(pa[m], vb, acc[m][di], 0, 0, 0);
        }
      }
      __syncthreads();
    }

    UNROLL for (int m = 0; m < 2; ++m)
      UNROLL for (int j = 0; j < 4; ++j) {
        float inv = 1.0f / lrow[m][j];
        int rowg = q0 + w * 32 + m * 16 + lh * 4 + j;
        bf16* ob = Out + ((size_t)(b * 2048) + rowg) * 4096 + h * 128 + l16;
        UNROLL for (int di = 0; di < 8; ++di)
          ob[di * 16] = (bf16)(acc[m][di][j] * inv);
      }
  }
}

// ---------------- launch ----------------
extern "C" void kernel_launch(void* const* d_in, const int* in_sizes, int n_in,
                              void* d_out, int out_size, void* d_ws, size_t ws_size,
                              hipStream_t stream) {
  const float* hidden = (const float*)d_in[0];
  const float* Wq = (const float*)d_in[3];
  const float* Wk = (const float*)d_in[4];
  const float* Wv = (const float*)d_in[5];
  const float* Wo = (const float*)d_in[6];
  float* out = (float*)d_out;

  char* ws = (char*)d_ws;
  if (ws_size < 184549376u) return;
  bf16* Xb = (bf16*)(ws);
  bf16* Wqkv = (bf16*)(ws + 33554432u);
  bf16* QKV = (bf16*)(ws + 83886080u);
  bf16* Qr = (bf16*)(ws + 134217728u);
  bf16* Kr = (bf16*)(ws + 167772160u);
  bf16* Vtg = (bf16*)(ws + 176160768u);
  bf16* AttnO = Xb;
  bf16* Wob = Wqkv;

  k_cvt<<<8192, 256, 0, stream>>>(hidden, Xb, 2097152);
  k_cvt<<<8192, 256, 0, stream>>>(Wq, Wqkv, 2097152);
  k_cvt<<<2048, 256, 0, stream>>>(Wk, Wqkv + 16777216u, 524288);
  k_cvt<<<2048, 256, 0, stream>>>(Wv, Wqkv + 20971520u, 524288);
  // QKV GEMM: 16 x 24 = 384 blocks (256^2 tiles, 4-deep rotation)
  k_gemm4d<bf16><<<384, 512, 0, stream>>>(Xb, Wqkv, QKV, 4096, 6144, 24);
  k_rope<<<40960, 256, 0, stream>>>(QKV, Qr, Kr);
  k_vtrans<<<1024, 256, 0, stream>>>(QKV, Vtg);
  k_cvt<<<8192, 256, 0, stream>>>(Wo, Wob, 2097152);
  k_flash<<<512, 256, 0, stream>>>(Qr, Kr, Vtg, AttnO);
  // O-proj: 16 x 16 = 256 blocks (one dispatch wave)
  k_gemm4d<float><<<256, 512, 0, stream>>>(AttnO, Wob, out, 4096, 4096, 16);
}

// Round 9
// 585.042 us; speedup vs baseline: 1.8699x; 1.0290x over previous
//
#include <hip/hip_runtime.h>
#include <hip/hip_bf16.h>

// Llama attention block: B=2, S=2048, H=4096, NH=32, NKV=8, HD=128, GQA 4:1.
// Pipeline (bf16 MFMA, fp32 accumulate):
//   1. convert hidden + Wq/Wk/Wv (concat) + Wo to bf16
//   2. QKV = X @ Wqkv^T  (M=4096,N=6144,K=4096): 256^2 8-phase GEMM with
//      SINGLE top-of-phase barrier (8 barriers/iter) + vmcnt(8) at even phases
//   3. RoPE (Q,K) + scatter; fold 1/sqrt(128) into Q
//   4. V transpose: QKV -> Vtg [b][hkv][128 d][2048 s]
//   5. flash attention (causal), QBLK=128, KV tile 64, dbuf LDS, paired blocks
//   6. out = AttnOut @ Wo^T (fp32), same GEMM

typedef __bf16 bf16;
typedef __bf16 bf16x8 __attribute__((ext_vector_type(8)));
typedef float f32x4 __attribute__((ext_vector_type(4)));

#define UNROLL _Pragma("unroll")

__device__ __forceinline__ void async16(const bf16* g, bf16* l) {
  __builtin_amdgcn_global_load_lds(
      (const __attribute__((address_space(1))) void*)g,
      (__attribute__((address_space(3))) void*)l,
      16, 0, 0);
}

#define BARR { __builtin_amdgcn_s_barrier(); __builtin_amdgcn_sched_barrier(0); }
#define VMCNT(n) { asm volatile("s_waitcnt vmcnt(" #n ")" ::: "memory"); __builtin_amdgcn_sched_barrier(0); }

// ---------------- fp32 -> bf16 convert (8 elem/thread) ----------------
__global__ void k_cvt(const float* __restrict__ s, bf16* __restrict__ d, int n8) {
  int i = blockIdx.x * 256 + threadIdx.x;
  if (i >= n8) return;
  const float4* sp = (const float4*)s + (size_t)i * 2;
  float4 a = sp[0], b = sp[1];
  bf16x8 o = { (bf16)a.x, (bf16)a.y, (bf16)a.z, (bf16)a.w,
               (bf16)b.x, (bf16)b.y, (bf16)b.z, (bf16)b.w };
  *(bf16x8*)(d + (size_t)i * 8) = o;
}

// ---------------- 256^2 single-barrier 8-phase GEMM: C = A * Bw^T --------
// 8 waves (2M x 4N), wave out 128x64. BK=64, 2 K-tiles/iter, 8 phases/iter.
// LDS: 2 sides x 4 units {A-kh0, A-kh1, B-kh0, B-kh1}, unit [256][32] bf16
// (16 KiB) = 128 KiB. Swizzle: byte p ^= ((p>>7)&3)<<4 (involution; inverse
// on global_load_lds source, forward on ds_read).
// Phase = [BARR; ds_reads; stage 1 unit (2 loads); lgkmcnt(0); 16 MFMA;
//          vmcnt(8) at even phases].  Single-barrier safety: a reader's
// lgkmcnt(0) precedes its barrier arrival; the writer stages only after
// passing that barrier -> 1-phase read->write gap is safe.
// Stage map (iter i, t0=2i, t1=t0+1): ph1:A(s1,k1,t1) ph2:B(s1,k1,t1)
// ph3:A(s0,k0,t0+2) ph4:B(s0,k0) ph5:A(s0,k1) ph6:B(s0,k1)
// ph7:A(s1,k0,t1+2) ph8:B(s1,k0).
// vmcnt(8) ledger (2 loads/phase): ph8 drains ph3,4 -> next ph1 reads ok;
// ph2 drains prev ph5,6 -> ph3 ok; ph4 drains prev ph7,8 -> ph5 ok;
// ph6 drains ph1,2 -> ph7 ok. Stage->read distance = 6 phases.
// Last iter: ph2 vm(8), ph4 vm(4), ph6 vm(0), ph8 none.
template <typename OutT>
__global__ __launch_bounds__(512, 2) void k_gemmSB(
    const bf16* __restrict__ A, const bf16* __restrict__ Bw,
    OutT* __restrict__ C, int K, int N, int nbx) {
  __shared__ __align__(16) bf16 lds[2][4][8192];  // 128 KiB
  const int tid = threadIdx.x;
  const int lane = tid & 63;
  const int w = tid >> 6;
  const int wm = w >> 2, wn = w & 3;  // 2M x 4N, wave out 128x64
  const int l16 = lane & 15, lh = lane >> 4;

  // XCD bijective swizzle (grid % 8 == 0)
  const int cpx = gridDim.x >> 3;
  const int swz = (blockIdx.x & 7) * cpx + (blockIdx.x >> 3);
  const int by = swz / nbx, bx = swz % nbx;
  const size_t m0 = (size_t)by * 256, n0 = (size_t)bx * 256;

  const int row0 = tid >> 2;
  const int cOff = ((tid & 3) ^ ((row0 >> 1) & 3)) * 8;
  const bf16* pA0 = A + (m0 + row0) * K + cOff;
  const bf16* pA1 = pA0 + (size_t)128 * K;
  const bf16* pB0 = Bw + (n0 + row0) * K + cOff;
  const bf16* pB1 = pB0 + (size_t)128 * K;

#define SA(s, h, t)                                        \
  { const int kk = (t) * 64 + (h) * 32;                    \
    async16(pA0 + kk, &lds[s][h][0] + tid * 8);            \
    async16(pA1 + kk, &lds[s][h][0] + 4096 + tid * 8); }
#define SB(s, h, t)                                        \
  { const int kk = (t) * 64 + (h) * 32;                    \
    async16(pB0 + kk, &lds[s][2 + (h)][0] + tid * 8);      \
    async16(pB1 + kk, &lds[s][2 + (h)][0] + 4096 + tid * 8); }

#define RDA(s, u, mh)                                                 \
  UNROLL for (int x = 0; x < 4; ++x) {                                \
    int p = (wm * 128 + (mh) * 64 + x * 16 + l16) * 64 + lh * 16;     \
    p ^= ((p >> 7) & 3) << 4;                                         \
    Ar[x] = *(const bf16x8*)((const char*)&lds[s][u][0] + p);         \
  }
#define RDB(s, u)                                                     \
  UNROLL for (int y = 0; y < 4; ++y) {                                \
    int p = (wn * 64 + y * 16 + l16) * 64 + lh * 16;                  \
    p ^= ((p >> 7) & 3) << 4;                                         \
    Br[y] = *(const bf16x8*)((const char*)&lds[s][u][0] + p);         \
  }
#define MF(mh)                                                        \
  { asm volatile("s_waitcnt lgkmcnt(0)" ::: "memory");                \
    __builtin_amdgcn_sched_barrier(0);                                \
    __builtin_amdgcn_s_setprio(1);                                    \
    UNROLL for (int x = 0; x < 4; ++x)                                \
      UNROLL for (int y = 0; y < 4; ++y)                              \
        acc[(mh) * 4 + x][y] = __builtin_amdgcn_mfma_f32_16x16x32_bf16( \
            Ar[x], Br[y], acc[(mh) * 4 + x][y], 0, 0, 0);             \
    __builtin_amdgcn_s_setprio(0); }

  f32x4 acc[8][4] = {};
  const int NITER = K >> 7;  // 2 K-tiles of 64 per iter

  // prologue: K-tile 0 fully + K-tile 1's kh0 units (12 loads)
  SA(0, 0, 0); SB(0, 0, 0); SA(0, 1, 0); SB(0, 1, 0); SA(1, 0, 1); SB(1, 0, 1);
  VMCNT(8);  // tile0-kh0 (A,B) landed

#define ITER_BODY(i, LAST)                                                  \
  { const int t0 = 2 * (i), t1 = t0 + 1;                                    \
    bf16x8 Ar[4], Br[4];                                                    \
    /* ph1 */ BARR; RDA(0, 0, 0); RDB(0, 2); SA(1, 1, t1); MF(0);           \
    /* ph2 */ BARR; RDA(0, 0, 1); SB(1, 1, t1); MF(1); VMCNT(8);            \
    /* ph3 */ BARR; RDA(0, 1, 0); RDB(0, 3);                                \
    if (!(LAST)) SA(0, 0, t0 + 2); MF(0);                                   \
    /* ph4 */ BARR; RDA(0, 1, 1); if (!(LAST)) SB(0, 0, t0 + 2); MF(1);     \
    if (LAST) { VMCNT(4); } else { VMCNT(8); }                              \
    /* ph5 */ BARR; RDA(1, 0, 0); RDB(1, 2);                                \
    if (!(LAST)) SA(0, 1, t0 + 2); MF(0);                                   \
    /* ph6 */ BARR; RDA(1, 0, 1); if (!(LAST)) SB(0, 1, t0 + 2); MF(1);     \
    if (LAST) { VMCNT(0); } else { VMCNT(8); }                              \
    /* ph7 */ BARR; RDA(1, 1, 0); RDB(1, 3);                                \
    if (!(LAST)) SA(1, 0, t1 + 2); MF(0);                                   \
    /* ph8 */ BARR; RDA(1, 1, 1); if (!(LAST)) SB(1, 0, t1 + 2); MF(1);     \
    if (!(LAST)) VMCNT(8); }

  for (int i = 0; i < NITER - 1; ++i) ITER_BODY(i, 0);
  ITER_BODY(NITER - 1, 1);

  // C write: row = m0 + wm*128 + mi*16 + lh*4 + j ; col = n0 + wn*64 + ni*16 + l16
  UNROLL for (int mi = 0; mi < 8; ++mi) {
    size_t row = m0 + wm * 128 + mi * 16 + lh * 4;
    UNROLL for (int ni = 0; ni < 4; ++ni) {
      size_t col = n0 + wn * 64 + ni * 16 + l16;
      UNROLL for (int j = 0; j < 4; ++j)
        C[(row + j) * N + col] = (OutT)acc[mi][ni][j];
    }
  }
#undef SA
#undef SB
#undef RDA
#undef RDB
#undef MF
#undef ITER_BODY
}

// ---------------- RoPE + scatter (Q,K only; V handled by k_vtrans) -------
__global__ void k_rope(const bf16* __restrict__ QKV, bf16* __restrict__ Qr,
                       bf16* __restrict__ Kr) {
  int gid = blockIdx.x * 256 + threadIdx.x;
  int p = gid & 63;
  int rest = gid >> 6;
  int slot = rest % 40;
  int tok = rest / 40;
  int s = tok & 2047;
  int b = tok >> 11;
  const bf16* src = QKV + (size_t)tok * 6144 + slot * 128;
  float x1 = (float)src[p], x2 = (float)src[p + 64];
  float f = exp2f((float)p * (-13.287712379549449f / 64.0f));
  float ang = (float)s * f;
  float sn, cn;
  sincosf(ang, &sn, &cn);
  float o1 = x1 * cn - x2 * sn;
  float o2 = x2 * cn + x1 * sn;
  bf16* dst;
  if (slot < 32) {
    o1 *= 0.08838834764831845f;
    o2 *= 0.08838834764831845f;
    dst = Qr + (((size_t)b * 32 + slot) * 2048 + s) * 128;
  } else {
    dst = Kr + (((size_t)b * 8 + (slot - 32)) * 2048 + s) * 128;
  }
  dst[p] = (bf16)o1;
  dst[p + 64] = (bf16)o2;
}

// ---------------- V transpose: QKV[tok][5120+hkv*128+d] -> Vtg[b][hkv][d][s]
__global__ void k_vtrans(const bf16* __restrict__ QKV, bf16* __restrict__ Vtg) {
  __shared__ __align__(16) bf16 T[64 * 64];
  const int tid = threadIdx.x;
  const int dt = blockIdx.x & 1;
  const int st = (blockIdx.x >> 1) & 31;
  const int hh = blockIdx.x >> 6;
  const int hkv = hh & 7, b = hh >> 3;
  const int s0 = st * 64, d0 = dt * 64;
  const bf16* src = QKV + (size_t)(b * 2048 + s0) * 6144 + 5120 + hkv * 128 + d0;
  UNROLL for (int k = 0; k < 2; ++k) {
    int cc = tid * 2 + k;
    int r = cc >> 3, c8 = cc & 7;
    bf16x8 v = *(const bf16x8*)(src + (size_t)r * 6144 + c8 * 8);
    int byte = (r * 128 + c8 * 16) ^ ((r & 7) << 4);
    *(bf16x8*)((char*)T + byte) = v;
  }
  __syncthreads();
  bf16* dst = Vtg + ((size_t)(b * 8 + hkv) * 128 + d0) * 2048 + s0;
  UNROLL for (int k = 0; k < 2; ++k) {
    int cc = tid * 2 + k;
    int d = cc >> 3, s8 = cc & 7;
    bf16x8 v;
    UNROLL for (int j = 0; j < 8; ++j) {
      int s = s8 * 8 + j;
      int byte = (s * 128 + d * 2) ^ ((s & 7) << 4);
      v[j] = *(const bf16*)((const char*)T + byte);
    }
    *(bf16x8*)(dst + (size_t)d * 2048 + s8 * 8) = v;
  }
}

// ---------------- flash attention (causal, GQA 4:1) — round-5 version ----
__global__ __launch_bounds__(256, 2) void k_flash(
    const bf16* __restrict__ Qr, const bf16* __restrict__ Kr,
    const bf16* __restrict__ Vtg, bf16* __restrict__ Out) {
  __shared__ __align__(16) bf16 Kl[2][64 * 128];
  __shared__ __align__(16) bf16 Vl[2][128 * 64];
  __shared__ __align__(16) bf16 Pl[4][32 * 64];
  const int tid = threadIdx.x;
  const int lane = tid & 63;
  const int w = tid >> 6;
  const int l16 = lane & 15, lh = lane >> 4;
  const int pid = blockIdx.x & 7;
  const int hl = blockIdx.x >> 3;
  const int h = hl & 31, b = hl >> 5;
  const int hkv = h >> 2;
  const bf16* Kbase = Kr + ((size_t)(b * 8 + hkv)) * 2048 * 128;
  const bf16* Vbase = Vtg + ((size_t)(b * 8 + hkv)) * 128 * 2048;
  bf16* P = &Pl[w][0];

  int kOff[4], vOff[4], ldsOff[4];
  UNROLL for (int i = 0; i < 4; ++i) {
    int c = (w * 4 + i) * 64 + lane;
    ldsOff[i] = c * 8;
    int r = c >> 4, p = c & 15;
    kOff[i] = r * 128 + (p ^ (r & 7)) * 8;
    int r2 = c >> 3, p2 = c & 7;
    vOff[i] = r2 * 2048 + (p2 ^ (r2 & 7)) * 8;
  }

  for (int qi = 0; qi < 2; ++qi) {
    const int q = qi ? (15 - pid) : pid;
    const int q0 = q * 128;
    const int nt = 2 * q + 2;

    bf16x8 qf[2][4];
    UNROLL for (int m = 0; m < 2; ++m) {
      const bf16* qb = Qr + (((size_t)(b * 32 + h)) * 2048 + q0 + w * 32 + m * 16 + l16) * 128 + lh * 8;
      UNROLL for (int kc = 0; kc < 4; ++kc) qf[m][kc] = *(const bf16x8*)(qb + kc * 32);
    }
    f32x4 acc[2][8] = {};
    float mrow[2][4] = {{-1e30f, -1e30f, -1e30f, -1e30f}, {-1e30f, -1e30f, -1e30f, -1e30f}};
    float lrow[2][4] = {};

    UNROLL for (int i = 0; i < 4; ++i) {
      async16(Kbase + kOff[i], &Kl[0][0] + ldsOff[i]);
      async16(Vbase + vOff[i], &Vl[0][0] + ldsOff[i]);
    }
    __syncthreads();

    for (int t = 0; t < nt; ++t) {
      const int cur = t & 1;
      if (t + 1 < nt) {
        const int nb = t + 1;
        UNROLL for (int i = 0; i < 4; ++i) {
          async16(Kbase + (size_t)nb * 8192 + kOff[i], &Kl[cur ^ 1][0] + ldsOff[i]);
          async16(Vbase + (size_t)nb * 64 + vOff[i], &Vl[cur ^ 1][0] + ldsOff[i]);
        }
      }
      f32x4 sf[2][4] = {};
      UNROLL for (int ni = 0; ni < 4; ++ni) {
        int row = ni * 16 + l16;
        bf16x8 kf[4];
        UNROLL for (int kc = 0; kc < 4; ++kc) {
          int byte = (row * 256 + kc * 64 + lh * 16) ^ ((row & 7) << 4);
          kf[kc] = *(const bf16x8*)((const char*)&Kl[cur][0] + byte);
        }
        UNROLL for (int m = 0; m < 2; ++m)
          UNROLL for (int kc = 0; kc < 4; ++kc)
            sf[m][ni] = __builtin_amdgcn_mfma_f32_16x16x32_bf16(qf[m][kc], kf[kc], sf[m][ni], 0, 0, 0);
      }
      if (t >= 2 * q) {
        UNROLL for (int m = 0; m < 2; ++m)
          UNROLL for (int ni = 0; ni < 4; ++ni) {
            int key = t * 64 + ni * 16 + l16;
            UNROLL for (int j = 0; j < 4; ++j) {
              int rowg = q0 + w * 32 + m * 16 + lh * 4 + j;
              if (key > rowg) sf[m][ni][j] = -1e30f;
            }
          }
      }
      float corr[2][4];
      UNROLL for (int m = 0; m < 2; ++m)
        UNROLL for (int j = 0; j < 4; ++j) {
          float mx = fmaxf(fmaxf(sf[m][0][j], sf[m][1][j]), fmaxf(sf[m][2][j], sf[m][3][j]));
          mx = fmaxf(mx, __shfl_xor(mx, 1));
          mx = fmaxf(mx, __shfl_xor(mx, 2));
          mx = fmaxf(mx, __shfl_xor(mx, 4));
          mx = fmaxf(mx, __shfl_xor(mx, 8));
          float mn = fmaxf(mrow[m][j], mx);
          corr[m][j] = __expf(mrow[m][j] - mn);
          mrow[m][j] = mn;
          float rs = 0.f;
          UNROLL for (int ni = 0; ni < 4; ++ni) {
            float pv = __expf(sf[m][ni][j] - mn);
            sf[m][ni][j] = pv;
            rs += pv;
          }
          rs += __shfl_xor(rs, 1);
          rs += __shfl_xor(rs, 2);
          rs += __shfl_xor(rs, 4);
          rs += __shfl_xor(rs, 8);
          lrow[m][j] = lrow[m][j] * corr[m][j] + rs;
        }
      UNROLL for (int m = 0; m < 2; ++m)
        UNROLL for (int di = 0; di < 8; ++di)
          UNROLL for (int j = 0; j < 4; ++j) acc[m][di][j] *= corr[m][j];
      UNROLL for (int m = 0; m < 2; ++m)
        UNROLL for (int ni = 0; ni < 4; ++ni)
          UNROLL for (int j = 0; j < 4; ++j) {
            int row = m * 16 + lh * 4 + j;
            int byte = (row * 128 + ni * 32 + l16 * 2) ^ ((row & 7) << 4);
            *(bf16*)((char*)P + byte) = (bf16)sf[m][ni][j];
          }
      UNROLL for (int kc = 0; kc < 2; ++kc) {
        bf16x8 pa[2];
        UNROLL for (int m = 0; m < 2; ++m) {
          int row = m * 16 + l16;
          int byte = (row * 128 + kc * 64 + lh * 16) ^ ((row & 7) << 4);
          pa[m] = *(const bf16x8*)((const char*)P + byte);
        }
        UNROLL for (int di = 0; di < 8; ++di) {
          int d = di * 16 + l16;
          int byte = (d * 128 + kc * 64 + lh * 16) ^ ((d & 7) << 4);
          bf16x8 vb = *(const bf16x8*)((const char*)&Vl[cur][0] + byte);
          UNROLL for (int m = 0; m < 2; ++m)
            acc[m][di] = __builtin_amdgcn_mfma_f32_16x16x32_bf16(pa[m], vb, acc[m][di], 0, 0, 0);
        }
      }
      __syncthreads();
    }

    UNROLL for (int m = 0; m < 2; ++m)
      UNROLL for (int j = 0; j < 4; ++j) {
        float inv = 1.0f / lrow[m][j];
        int rowg = q0 + w * 32 + m * 16 + lh * 4 + j;
        bf16* ob = Out + ((size_t)(b * 2048) + rowg) * 4096 + h * 128 + l16;
        UNROLL for (int di = 0; di < 8; ++di)
          ob[di * 16] = (bf16)(acc[m][di][j] * inv);
      }
  }
}

// ---------------- launch ----------------
extern "C" void kernel_launch(void* const* d_in, const int* in_sizes, int n_in,
                              void* d_out, int out_size, void* d_ws, size_t ws_size,
                              hipStream_t stream) {
  const float* hidden = (const float*)d_in[0];
  const float* Wq = (const float*)d_in[3];
  const float* Wk = (const float*)d_in[4];
  const float* Wv = (const float*)d_in[5];
  const float* Wo = (const float*)d_in[6];
  float* out = (float*)d_out;

  char* ws = (char*)d_ws;
  if (ws_size < 184549376u) return;
  bf16* Xb = (bf16*)(ws);
  bf16* Wqkv = (bf16*)(ws + 33554432u);
  bf16* QKV = (bf16*)(ws + 83886080u);
  bf16* Qr = (bf16*)(ws + 134217728u);
  bf16* Kr = (bf16*)(ws + 167772160u);
  bf16* Vtg = (bf16*)(ws + 176160768u);
  bf16* AttnO = Xb;
  bf16* Wob = Wqkv;

  k_cvt<<<8192, 256, 0, stream>>>(hidden, Xb, 2097152);
  k_cvt<<<8192, 256, 0, stream>>>(Wq, Wqkv, 2097152);
  k_cvt<<<2048, 256, 0, stream>>>(Wk, Wqkv + 16777216u, 524288);
  k_cvt<<<2048, 256, 0, stream>>>(Wv, Wqkv + 20971520u, 524288);
  // QKV GEMM: 16 x 24 = 384 blocks (256^2 tiles, single-barrier 8-phase)
  k_gemmSB<bf16><<<384, 512, 0, stream>>>(Xb, Wqkv, QKV, 4096, 6144, 24);
  k_rope<<<40960, 256, 0, stream>>>(QKV, Qr, Kr);
  k_vtrans<<<1024, 256, 0, stream>>>(QKV, Vtg);
  k_cvt<<<8192, 256, 0, stream>>>(Wo, Wob, 2097152);
  k_flash<<<512, 256, 0, stream>>>(Qr, Kr, Vtg, AttnO);
  // O-proj: 16 x 16 = 256 blocks (one dispatch wave)
  k_gemmSB<float><<<256, 512, 0, stream>>>(AttnO, Wob, out, 4096, 4096, 16);
}

// Round 10
// 581.171 us; speedup vs baseline: 1.8824x; 1.0067x over previous
//
#include <hip/hip_runtime.h>
#include <hip/hip_bf16.h>

// Llama attention block: B=2, S=2048, H=4096, NH=32, NKV=8, HD=128, GQA 4:1.
// Pipeline (bf16 MFMA, fp32 accumulate):
//   1. convert hidden + Wq/Wk/Wv (concat) + Wo to bf16
//   2. QKV = X @ Wqkv^T  (M=4096,N=6144,K=4096): 256^2 8-phase GEMM,
//      single top-of-phase barrier, counted vmcnt(8); COMPILER-SCHEDULED
//      (no sched_barrier / no explicit lgkmcnt — m141/m97 evidence)
//   3. RoPE (Q,K) + scatter; fold 1/sqrt(128) into Q
//   4. V transpose: QKV -> Vtg [b][hkv][128 d][2048 s]
//   5. flash attention (causal), QBLK=128, KV tile 64, dbuf LDS, paired blocks
//   6. out = AttnOut @ Wo^T (fp32), same GEMM

typedef __bf16 bf16;
typedef __bf16 bf16x8 __attribute__((ext_vector_type(8)));
typedef float f32x4 __attribute__((ext_vector_type(4)));

#define UNROLL _Pragma("unroll")

__device__ __forceinline__ void async16(const bf16* g, bf16* l) {
  __builtin_amdgcn_global_load_lds(
      (const __attribute__((address_space(1))) void*)g,
      (__attribute__((address_space(3))) void*)l,
      16, 0, 0);
}

// Bare barrier; vmcnt pins VMEM ops only (memory clobber) — the compiler
// is otherwise free to schedule ds_reads, lgkmcnt splits, and address VALU.
#define BARR { __builtin_amdgcn_s_barrier(); }
#define VMCNT(n) { asm volatile("s_waitcnt vmcnt(" #n ")" ::: "memory"); }

// ---------------- fp32 -> bf16 convert (8 elem/thread) ----------------
__global__ void k_cvt(const float* __restrict__ s, bf16* __restrict__ d, int n8) {
  int i = blockIdx.x * 256 + threadIdx.x;
  if (i >= n8) return;
  const float4* sp = (const float4*)s + (size_t)i * 2;
  float4 a = sp[0], b = sp[1];
  bf16x8 o = { (bf16)a.x, (bf16)a.y, (bf16)a.z, (bf16)a.w,
               (bf16)b.x, (bf16)b.y, (bf16)b.z, (bf16)b.w };
  *(bf16x8*)(d + (size_t)i * 8) = o;
}

// ---------------- 256^2 single-barrier 8-phase GEMM: C = A * Bw^T --------
// 8 waves (2M x 4N), wave out 128x64. BK=64, 2 K-tiles/iter, 8 phases/iter.
// LDS: 2 sides x 4 units {A-kh0, A-kh1, B-kh0, B-kh1}, unit [256][32] bf16
// (16 KiB) = 128 KiB. Swizzle: byte p ^= ((p>>7)&3)<<4 (involution; inverse
// on global_load_lds source, forward on ds_read).
// Phase = [BARR; ds_reads (C++ loads -> compiler lgkmcnt); stage 1 unit;
//          setprio(1); 16 MFMA; setprio(0); vmcnt(8) at even phases].
// vmcnt(8) ledger (2 loads/stage, 1 stage/phase, steady 8 outstanding at
// iter entry): ph2 drains prev ph5,6 (s0k1) -> ph3 reads ok; ph4 drains
// prev ph7,8 (s1k0) -> ph5 ok; ph6 drains ph1,2 (s1k1) -> ph7 ok; ph8
// drains ph3,4 (s0k0,t0+2) -> next ph1 ok. Stage->read distance 5-6 phases.
// WAR: every staged unit is dead for 6 phases; barriers keep wave skew <=1
// phase, so compiler-local reordering cannot violate it.
// Last iter: ph2 vm(8), ph4 vm(4), ph6 vm(0), ph8 none.
template <typename OutT>
__global__ __launch_bounds__(512, 2) void k_gemmCS(
    const bf16* __restrict__ A, const bf16* __restrict__ Bw,
    OutT* __restrict__ C, int K, int N, int nbx) {
  __shared__ __align__(16) bf16 lds[2][4][8192];  // 128 KiB
  const int tid = threadIdx.x;
  const int lane = tid & 63;
  const int w = tid >> 6;
  const int wm = w >> 2, wn = w & 3;  // 2M x 4N, wave out 128x64
  const int l16 = lane & 15, lh = lane >> 4;

  // XCD bijective swizzle (grid % 8 == 0)
  const int cpx = gridDim.x >> 3;
  const int swz = (blockIdx.x & 7) * cpx + (blockIdx.x >> 3);
  const int by = swz / nbx, bx = swz % nbx;
  const size_t m0 = (size_t)by * 256, n0 = (size_t)bx * 256;

  const int row0 = tid >> 2;
  const int cOff = ((tid & 3) ^ ((row0 >> 1) & 3)) * 8;
  const bf16* pA0 = A + (m0 + row0) * K + cOff;
  const bf16* pA1 = pA0 + (size_t)128 * K;
  const bf16* pB0 = Bw + (n0 + row0) * K + cOff;
  const bf16* pB1 = pB0 + (size_t)128 * K;

#define SA(s, h, t)                                        \
  { const int kk = (t) * 64 + (h) * 32;                    \
    async16(pA0 + kk, &lds[s][h][0] + tid * 8);            \
    async16(pA1 + kk, &lds[s][h][0] + 4096 + tid * 8); }
#define SB(s, h, t)                                        \
  { const int kk = (t) * 64 + (h) * 32;                    \
    async16(pB0 + kk, &lds[s][2 + (h)][0] + tid * 8);      \
    async16(pB1 + kk, &lds[s][2 + (h)][0] + 4096 + tid * 8); }

#define RDA(s, u, mh)                                                 \
  UNROLL for (int x = 0; x < 4; ++x) {                                \
    int p = (wm * 128 + (mh) * 64 + x * 16 + l16) * 64 + lh * 16;     \
    p ^= ((p >> 7) & 3) << 4;                                         \
    Ar[x] = *(const bf16x8*)((const char*)&lds[s][u][0] + p);         \
  }
#define RDB(s, u)                                                     \
  UNROLL for (int y = 0; y < 4; ++y) {                                \
    int p = (wn * 64 + y * 16 + l16) * 64 + lh * 16;                  \
    p ^= ((p >> 7) & 3) << 4;                                         \
    Br[y] = *(const bf16x8*)((const char*)&lds[s][u][0] + p);         \
  }
#define MF(mh)                                                        \
  { __builtin_amdgcn_s_setprio(1);                                    \
    UNROLL for (int x = 0; x < 4; ++x)                                \
      UNROLL for (int y = 0; y < 4; ++y)                              \
        acc[(mh) * 4 + x][y] = __builtin_amdgcn_mfma_f32_16x16x32_bf16( \
            Ar[x], Br[y], acc[(mh) * 4 + x][y], 0, 0, 0);             \
    __builtin_amdgcn_s_setprio(0); }

  f32x4 acc[8][4] = {};
  const int NITER = K >> 7;  // 2 K-tiles of 64 per iter

  // prologue: K-tile 0 fully + K-tile 1's kh0 units (12 loads)
  SA(0, 0, 0); SB(0, 0, 0); SA(0, 1, 0); SB(0, 1, 0); SA(1, 0, 1); SB(1, 0, 1);
  VMCNT(8);  // tile0-kh0 (A,B) landed

#define ITER_BODY(i, LAST)                                                  \
  { const int t0 = 2 * (i), t1 = t0 + 1;                                    \
    bf16x8 Ar[4], Br[4];                                                    \
    /* ph1 */ BARR; RDA(0, 0, 0); RDB(0, 2); SA(1, 1, t1); MF(0);           \
    /* ph2 */ BARR; RDA(0, 0, 1); SB(1, 1, t1); MF(1); VMCNT(8);            \
    /* ph3 */ BARR; RDA(0, 1, 0); RDB(0, 3);                                \
    if (!(LAST)) SA(0, 0, t0 + 2); MF(0);                                   \
    /* ph4 */ BARR; RDA(0, 1, 1); if (!(LAST)) SB(0, 0, t0 + 2); MF(1);     \
    if (LAST) { VMCNT(4); } else { VMCNT(8); }                              \
    /* ph5 */ BARR; RDA(1, 0, 0); RDB(1, 2);                                \
    if (!(LAST)) SA(0, 1, t0 + 2); MF(0);                                   \
    /* ph6 */ BARR; RDA(1, 0, 1); if (!(LAST)) SB(0, 1, t0 + 2); MF(1);     \
    if (LAST) { VMCNT(0); } else { VMCNT(8); }                              \
    /* ph7 */ BARR; RDA(1, 1, 0); RDB(1, 3);                                \
    if (!(LAST)) SA(1, 0, t1 + 2); MF(0);                                   \
    /* ph8 */ BARR; RDA(1, 1, 1); if (!(LAST)) SB(1, 0, t1 + 2); MF(1);     \
    if (!(LAST)) VMCNT(8); }

  for (int i = 0; i < NITER - 1; ++i) ITER_BODY(i, 0);
  ITER_BODY(NITER - 1, 1);

  // C write: row = m0 + wm*128 + mi*16 + lh*4 + j ; col = n0 + wn*64 + ni*16 + l16
  UNROLL for (int mi = 0; mi < 8; ++mi) {
    size_t row = m0 + wm * 128 + mi * 16 + lh * 4;
    UNROLL for (int ni = 0; ni < 4; ++ni) {
      size_t col = n0 + wn * 64 + ni * 16 + l16;
      UNROLL for (int j = 0; j < 4; ++j)
        C[(row + j) * N + col] = (OutT)acc[mi][ni][j];
    }
  }
#undef SA
#undef SB
#undef RDA
#undef RDB
#undef MF
#undef ITER_BODY
}

// ---------------- RoPE + scatter (Q,K only; V handled by k_vtrans) -------
__global__ void k_rope(const bf16* __restrict__ QKV, bf16* __restrict__ Qr,
                       bf16* __restrict__ Kr) {
  int gid = blockIdx.x * 256 + threadIdx.x;
  int p = gid & 63;
  int rest = gid >> 6;
  int slot = rest % 40;
  int tok = rest / 40;
  int s = tok & 2047;
  int b = tok >> 11;
  const bf16* src = QKV + (size_t)tok * 6144 + slot * 128;
  float x1 = (float)src[p], x2 = (float)src[p + 64];
  float f = exp2f((float)p * (-13.287712379549449f / 64.0f));
  float ang = (float)s * f;
  float sn, cn;
  sincosf(ang, &sn, &cn);
  float o1 = x1 * cn - x2 * sn;
  float o2 = x2 * cn + x1 * sn;
  bf16* dst;
  if (slot < 32) {
    o1 *= 0.08838834764831845f;
    o2 *= 0.08838834764831845f;
    dst = Qr + (((size_t)b * 32 + slot) * 2048 + s) * 128;
  } else {
    dst = Kr + (((size_t)b * 8 + (slot - 32)) * 2048 + s) * 128;
  }
  dst[p] = (bf16)o1;
  dst[p + 64] = (bf16)o2;
}

// ---------------- V transpose: QKV[tok][5120+hkv*128+d] -> Vtg[b][hkv][d][s]
__global__ void k_vtrans(const bf16* __restrict__ QKV, bf16* __restrict__ Vtg) {
  __shared__ __align__(16) bf16 T[64 * 64];
  const int tid = threadIdx.x;
  const int dt = blockIdx.x & 1;
  const int st = (blockIdx.x >> 1) & 31;
  const int hh = blockIdx.x >> 6;
  const int hkv = hh & 7, b = hh >> 3;
  const int s0 = st * 64, d0 = dt * 64;
  const bf16* src = QKV + (size_t)(b * 2048 + s0) * 6144 + 5120 + hkv * 128 + d0;
  UNROLL for (int k = 0; k < 2; ++k) {
    int cc = tid * 2 + k;
    int r = cc >> 3, c8 = cc & 7;
    bf16x8 v = *(const bf16x8*)(src + (size_t)r * 6144 + c8 * 8);
    int byte = (r * 128 + c8 * 16) ^ ((r & 7) << 4);
    *(bf16x8*)((char*)T + byte) = v;
  }
  __syncthreads();
  bf16* dst = Vtg + ((size_t)(b * 8 + hkv) * 128 + d0) * 2048 + s0;
  UNROLL for (int k = 0; k < 2; ++k) {
    int cc = tid * 2 + k;
    int d = cc >> 3, s8 = cc & 7;
    bf16x8 v;
    UNROLL for (int j = 0; j < 8; ++j) {
      int s = s8 * 8 + j;
      int byte = (s * 128 + d * 2) ^ ((s & 7) << 4);
      v[j] = *(const bf16*)((const char*)T + byte);
    }
    *(bf16x8*)(dst + (size_t)d * 2048 + s8 * 8) = v;
  }
}

// ---------------- flash attention (causal, GQA 4:1) — round-5 version ----
__global__ __launch_bounds__(256, 2) void k_flash(
    const bf16* __restrict__ Qr, const bf16* __restrict__ Kr,
    const bf16* __restrict__ Vtg, bf16* __restrict__ Out) {
  __shared__ __align__(16) bf16 Kl[2][64 * 128];
  __shared__ __align__(16) bf16 Vl[2][128 * 64];
  __shared__ __align__(16) bf16 Pl[4][32 * 64];
  const int tid = threadIdx.x;
  const int lane = tid & 63;
  const int w = tid >> 6;
  const int l16 = lane & 15, lh = lane >> 4;
  const int pid = blockIdx.x & 7;
  const int hl = blockIdx.x >> 3;
  const int h = hl & 31, b = hl >> 5;
  const int hkv = h >> 2;
  const bf16* Kbase = Kr + ((size_t)(b * 8 + hkv)) * 2048 * 128;
  const bf16* Vbase = Vtg + ((size_t)(b * 8 + hkv)) * 128 * 2048;
  bf16* P = &Pl[w][0];

  int kOff[4], vOff[4], ldsOff[4];
  UNROLL for (int i = 0; i < 4; ++i) {
    int c = (w * 4 + i) * 64 + lane;
    ldsOff[i] = c * 8;
    int r = c >> 4, p = c & 15;
    kOff[i] = r * 128 + (p ^ (r & 7)) * 8;
    int r2 = c >> 3, p2 = c & 7;
    vOff[i] = r2 * 2048 + (p2 ^ (r2 & 7)) * 8;
  }

  for (int qi = 0; qi < 2; ++qi) {
    const int q = qi ? (15 - pid) : pid;
    const int q0 = q * 128;
    const int nt = 2 * q + 2;

    bf16x8 qf[2][4];
    UNROLL for (int m = 0; m < 2; ++m) {
      const bf16* qb = Qr + (((size_t)(b * 32 + h)) * 2048 + q0 + w * 32 + m * 16 + l16) * 128 + lh * 8;
      UNROLL for (int kc = 0; kc < 4; ++kc) qf[m][kc] = *(const bf16x8*)(qb + kc * 32);
    }
    f32x4 acc[2][8] = {};
    float mrow[2][4] = {{-1e30f, -1e30f, -1e30f, -1e30f}, {-1e30f, -1e30f, -1e30f, -1e30f}};
    float lrow[2][4] = {};

    UNROLL for (int i = 0; i < 4; ++i) {
      async16(Kbase + kOff[i], &Kl[0][0] + ldsOff[i]);
      async16(Vbase + vOff[i], &Vl[0][0] + ldsOff[i]);
    }
    __syncthreads();

    for (int t = 0; t < nt; ++t) {
      const int cur = t & 1;
      if (t + 1 < nt) {
        const int nb = t + 1;
        UNROLL for (int i = 0; i < 4; ++i) {
          async16(Kbase + (size_t)nb * 8192 + kOff[i], &Kl[cur ^ 1][0] + ldsOff[i]);
          async16(Vbase + (size_t)nb * 64 + vOff[i], &Vl[cur ^ 1][0] + ldsOff[i]);
        }
      }
      f32x4 sf[2][4] = {};
      UNROLL for (int ni = 0; ni < 4; ++ni) {
        int row = ni * 16 + l16;
        bf16x8 kf[4];
        UNROLL for (int kc = 0; kc < 4; ++kc) {
          int byte = (row * 256 + kc * 64 + lh * 16) ^ ((row & 7) << 4);
          kf[kc] = *(const bf16x8*)((const char*)&Kl[cur][0] + byte);
        }
        UNROLL for (int m = 0; m < 2; ++m)
          UNROLL for (int kc = 0; kc < 4; ++kc)
            sf[m][ni] = __builtin_amdgcn_mfma_f32_16x16x32_bf16(qf[m][kc], kf[kc], sf[m][ni], 0, 0, 0);
      }
      if (t >= 2 * q) {
        UNROLL for (int m = 0; m < 2; ++m)
          UNROLL for (int ni = 0; ni < 4; ++ni) {
            int key = t * 64 + ni * 16 + l16;
            UNROLL for (int j = 0; j < 4; ++j) {
              int rowg = q0 + w * 32 + m * 16 + lh * 4 + j;
              if (key > rowg) sf[m][ni][j] = -1e30f;
            }
          }
      }
      float corr[2][4];
      UNROLL for (int m = 0; m < 2; ++m)
        UNROLL for (int j = 0; j < 4; ++j) {
          float mx = fmaxf(fmaxf(sf[m][0][j], sf[m][1][j]), fmaxf(sf[m][2][j], sf[m][3][j]));
          mx = fmaxf(mx, __shfl_xor(mx, 1));
          mx = fmaxf(mx, __shfl_xor(mx, 2));
          mx = fmaxf(mx, __shfl_xor(mx, 4));
          mx = fmaxf(mx, __shfl_xor(mx, 8));
          float mn = fmaxf(mrow[m][j], mx);
          corr[m][j] = __expf(mrow[m][j] - mn);
          mrow[m][j] = mn;
          float rs = 0.f;
          UNROLL for (int ni = 0; ni < 4; ++ni) {
            float pv = __expf(sf[m][ni][j] - mn);
            sf[m][ni][j] = pv;
            rs += pv;
          }
          rs += __shfl_xor(rs, 1);
          rs += __shfl_xor(rs, 2);
          rs += __shfl_xor(rs, 4);
          rs += __shfl_xor(rs, 8);
          lrow[m][j] = lrow[m][j] * corr[m][j] + rs;
        }
      UNROLL for (int m = 0; m < 2; ++m)
        UNROLL for (int di = 0; di < 8; ++di)
          UNROLL for (int j = 0; j < 4; ++j) acc[m][di][j] *= corr[m][j];
      UNROLL for (int m = 0; m < 2; ++m)
        UNROLL for (int ni = 0; ni < 4; ++ni)
          UNROLL for (int j = 0; j < 4; ++j) {
            int row = m * 16 + lh * 4 + j;
            int byte = (row * 128 + ni * 32 + l16 * 2) ^ ((row & 7) << 4);
            *(bf16*)((char*)P + byte) = (bf16)sf[m][ni][j];
          }
      UNROLL for (int kc = 0; kc < 2; ++kc) {
        bf16x8 pa[2];
        UNROLL for (int m = 0; m < 2; ++m) {
          int row = m * 16 + l16;
          int byte = (row * 128 + kc * 64 + lh * 16) ^ ((row & 7) << 4);
          pa[m] = *(const bf16x8*)((const char*)P + byte);
        }
        UNROLL for (int di = 0; di < 8; ++di) {
          int d = di * 16 + l16;
          int byte = (d * 128 + kc * 64 + lh * 16) ^ ((d & 7) << 4);
          bf16x8 vb = *(const bf16x8*)((const char*)&Vl[cur][0] + byte);
          UNROLL for (int m = 0; m < 2; ++m)
            acc[m][di] = __builtin_amdgcn_mfma_f32_16x16x32_bf16(pa[m], vb, acc[m][di], 0, 0, 0);
        }
      }
      __syncthreads();
    }

    UNROLL for (int m = 0; m < 2; ++m)
      UNROLL for (int j = 0; j < 4; ++j) {
        float inv = 1.0f / lrow[m][j];
        int rowg = q0 + w * 32 + m * 16 + lh * 4 + j;
        bf16* ob = Out + ((size_t)(b * 2048) + rowg) * 4096 + h * 128 + l16;
        UNROLL for (int di = 0; di < 8; ++di)
          ob[di * 16] = (bf16)(acc[m][di][j] * inv);
      }
  }
}

// ---------------- launch ----------------
extern "C" void kernel_launch(void* const* d_in, const int* in_sizes, int n_in,
                              void* d_out, int out_size, void* d_ws, size_t ws_size,
                              hipStream_t stream) {
  const float* hidden = (const float*)d_in[0];
  const float* Wq = (const float*)d_in[3];
  const float* Wk = (const float*)d_in[4];
  const float* Wv = (const float*)d_in[5];
  const float* Wo = (const float*)d_in[6];
  float* out = (float*)d_out;

  char* ws = (char*)d_ws;
  if (ws_size < 184549376u) return;
  bf16* Xb = (bf16*)(ws);
  bf16* Wqkv = (bf16*)(ws + 33554432u);
  bf16* QKV = (bf16*)(ws + 83886080u);
  bf16* Qr = (bf16*)(ws + 134217728u);
  bf16* Kr = (bf16*)(ws + 167772160u);
  bf16* Vtg = (bf16*)(ws + 176160768u);
  bf16* AttnO = Xb;
  bf16* Wob = Wqkv;

  k_cvt<<<8192, 256, 0, stream>>>(hidden, Xb, 2097152);
  k_cvt<<<8192, 256, 0, stream>>>(Wq, Wqkv, 2097152);
  k_cvt<<<2048, 256, 0, stream>>>(Wk, Wqkv + 16777216u, 524288);
  k_cvt<<<2048, 256, 0, stream>>>(Wv, Wqkv + 20971520u, 524288);
  // QKV GEMM: 16 x 24 = 384 blocks (256^2 tiles, compiler-scheduled phases)
  k_gemmCS<bf16><<<384, 512, 0, stream>>>(Xb, Wqkv, QKV, 4096, 6144, 24);
  k_rope<<<40960, 256, 0, stream>>>(QKV, Qr, Kr);
  k_vtrans<<<1024, 256, 0, stream>>>(QKV, Vtg);
  k_cvt<<<8192, 256, 0, stream>>>(Wo, Wob, 2097152);
  k_flash<<<512, 256, 0, stream>>>(Qr, Kr, Vtg, AttnO);
  // O-proj: 16 x 16 = 256 blocks (one dispatch wave)
  k_gemmCS<float><<<256, 512, 0, stream>>>(AttnO, Wob, out, 4096, 4096, 16);
}